// Round 14
// baseline (224.711 us; speedup 1.0000x reference)
//
#include <hip/hip_runtime.h>

typedef unsigned short u16;
typedef __attribute__((ext_vector_type(8))) short v8s;
typedef __attribute__((ext_vector_type(4))) float v4f;

#define S_LEN 2048
#define HID   2048
#define NH    32
#define NKV   8
#define HD    64
#define DVV   128
#define LAMBDA_INIT  0.7455692280263525f
#define ONE_MINUS_LI 0.2544307719736475f
#define EXP2_SCALE   0.18033688011112042f   // 0.125 * log2(e)

__device__ __forceinline__ u16 f2b(float f){
  union { float f; unsigned int i; } v; v.f = f;
  unsigned int x = v.i;
  unsigned int r = (x + 0x7fffu + ((x >> 16) & 1u)) >> 16;
  return (u16)r;
}
// truncating bf16 (P-store only: P>=0, feeds PV matmul; saves 3 VALU/value)
__device__ __forceinline__ u16 f2b_t(float f){
  union { float f; unsigned int i; } v; v.f = f;
  return (u16)(v.i >> 16);
}
__device__ __forceinline__ float b2f(u16 u){
  union { unsigned int i; float f; } v; v.i = ((unsigned int)u) << 16; return v.f;
}

__device__ __forceinline__ void gld16(const u16* g, u16* l){
  __builtin_amdgcn_global_load_lds(
      (const __attribute__((address_space(1))) unsigned int*)g,
      (__attribute__((address_space(3))) unsigned int*)l, 16, 0, 0);
}

// one launch casting hs, Wq, Wk, Wv, Wo to bf16 (regions by blockIdx)
__global__ __launch_bounds__(256) void cast5(
    const float* __restrict__ hs, const float* __restrict__ Wq,
    const float* __restrict__ Wk, const float* __restrict__ Wv,
    const float* __restrict__ Wo,
    u16* __restrict__ hsb, u16* __restrict__ Wqkvb, u16* __restrict__ Wob)
{
  int b = blockIdx.x;
  const float* S; u16* D; int rb;
  if (b < 2048)      { S = hs; D = hsb;             rb = b; }
  else if (b < 4096) { S = Wq; D = Wqkvb;           rb = b - 2048; }
  else if (b < 4608) { S = Wk; D = Wqkvb + 4194304; rb = b - 4096; }
  else if (b < 5120) { S = Wv; D = Wqkvb + 5242880; rb = b - 4608; }
  else               { S = Wo; D = Wob;             rb = b - 5120; }
  size_t i = ((size_t)rb * 256 + threadIdx.x) * 8;
  float4 a = *(const float4*)(S + i);
  float4 c = *(const float4*)(S + i + 4);
  u16 o[8] = {f2b(a.x), f2b(a.y), f2b(a.z), f2b(a.w), f2b(c.x), f2b(c.y), f2b(c.z), f2b(c.w)};
  *(uint4*)(D + i) = *(const uint4*)o;
}

// C[m][n] = sum_k A[m*K+k]*B[n*K+k]; A,B bf16.
// 128x64 tile, BK=64, DEPTH-buffered LDS (DEPTH=2: 48 KB -> 3 blocks/CU;
// DEPTH=3: 72 KB -> 2 blocks/CU with counted vmcnt(6) waits = 2 iters of
// load slack, T4-style). gemm<2> uses DEPTH=2 (occupancy 3 wins, R12 lesson);
// gemm<0> uses DEPTH=3 (occupancy already 2 -> pipeline depth is free).
// MODE 0: C fp32 to Cv.
// MODE 2: fused QKV epilogue — Q cols (n0<2048) / K cols (2048..2559) get
// RoPE in registers -> Qbf/Kbf (h,s,d); V cols (n0>=2560) transposed through
// LDS (reusing As) -> Vt (8,64,S).
template<int MODE, int DEPTH>
__global__ __launch_bounds__(256) void gemm_bf16(const u16* __restrict__ A, const u16* __restrict__ B,
                                                 void* __restrict__ Cv, int M, int N, int K,
                                                 const float* __restrict__ cosb, const float* __restrict__ sinb,
                                                 u16* __restrict__ Qbf, u16* __restrict__ Kbf,
                                                 u16* __restrict__ Vtp)
{
  __shared__ __attribute__((aligned(16))) u16 As[DEPTH][128*64];
  __shared__ __attribute__((aligned(16))) u16 Bs[DEPTH][64*64];
  const int t    = threadIdx.x;
  const int w    = t >> 6, lane = t & 63;
  const int mm   = lane & 15, g = lane >> 4;
  const int m0   = blockIdx.y * 128, n0 = blockIdx.x * 64;
  const int lr   = lane >> 3;      // 0..7
  const int sch  = lane & 7;

  v4f acc[2][4];
#pragma unroll
  for (int i = 0; i < 2; i++)
#pragma unroll
    for (int j = 0; j < 4; j++) acc[i][j] = (v4f){0.f,0.f,0.f,0.f};

// 6 gld16 per thread per stage (4 A + 2 B) — vmcnt counting relies on this
#define G_STAGE(kk, buf) do { \
    _Pragma("unroll") \
    for (int i = 0; i < 4; i++){ \
      int r  = w*32 + lr + i*8; \
      int ce = ((sch ^ (r & 7)) * 8); \
      gld16(A + (size_t)(m0 + r) * K + (kk) + ce, &As[buf][w*2048 + i*512]); \
    } \
    _Pragma("unroll") \
    for (int i = 0; i < 2; i++){ \
      int r  = w*16 + lr + i*8; \
      int ce = ((sch ^ (r & 7)) * 8); \
      gld16(B + (size_t)(n0 + r) * K + (kk) + ce, &Bs[buf][w*1024 + i*512]); \
    } \
  } while(0)

  // prologue: stage tile 0 (and tile 1 for DEPTH=3), full drain
  G_STAGE(0, 0);
  if (DEPTH >= 3 && 64 < K) G_STAGE(64, 1);
  __syncthreads();

  for (int k0 = 0; k0 < K; k0 += 64){
    const int cur = (k0 >> 6) % DEPTH;
    if (k0){
      if (DEPTH >= 3 && k0 + 64 < K){
        // tile k0 + tile k0+64 outstanding (6 each): wait only tile k0's
        asm volatile("s_waitcnt vmcnt(6)" ::: "memory");
      } else {
        asm volatile("s_waitcnt vmcnt(0)" ::: "memory");
      }
      __builtin_amdgcn_s_barrier();
      __builtin_amdgcn_sched_barrier(0);
    }
    if (DEPTH == 2){
      if (k0 + 64 < K) G_STAGE(k0 + 64, cur ^ 1);
    } else {
      if (k0 + 128 < K) G_STAGE(k0 + 128, ((k0 >> 6) + 2) % DEPTH);
    }

#pragma unroll
    for (int kc = 0; kc < 2; kc++){
      v8s af[2], bf[4];
#pragma unroll
      for (int i = 0; i < 2; i++){
        int r = w*32 + i*16 + mm;
        af[i] = *(const v8s*)&As[cur][r*64 + (((kc*4 + g) ^ (r & 7)) * 8)];
      }
#pragma unroll
      for (int j = 0; j < 4; j++){
        int r = j*16 + mm;
        bf[j] = *(const v8s*)&Bs[cur][r*64 + (((kc*4 + g) ^ (r & 7)) * 8)];
      }
#pragma unroll
      for (int i = 0; i < 2; i++)
#pragma unroll
        for (int j = 0; j < 4; j++)
          acc[i][j] = __builtin_amdgcn_mfma_f32_16x16x32_bf16(af[i], bf[j], acc[i][j], 0, 0, 0);
    }
  }
#undef G_STAGE

  if (MODE == 2 && n0 < 2560){
    // Q or K columns: RoPE in registers, write (h,s,d) layout
    u16* base = (n0 < 2048) ? (Qbf + (size_t)(n0 >> 6) * S_LEN * HD)
                            : (Kbf + (size_t)((n0 - 2048) >> 6) * S_LEN * HD);
#pragma unroll
    for (int i = 0; i < 2; i++)
#pragma unroll
      for (int j = 0; j < 2; j++)
#pragma unroll
        for (int r = 0; r < 4; r++){
          int s = m0 + w*32 + i*16 + g*4 + r;
          int d = j*16 + mm;
          float x1 = acc[i][j][r], x2 = acc[i][j+2][r];
          float c1 = cosb[s*HD + d],      s1 = sinb[s*HD + d];
          float c2 = cosb[s*HD + d + 32], s2 = sinb[s*HD + d + 32];
          base[(size_t)s*HD + d]      = f2b(x1*c1 - x2*s1);
          base[(size_t)s*HD + d + 32] = f2b(x2*c2 + x1*s2);
        }
  } else if (MODE == 2){
    // V columns: transpose through LDS (As is dead) -> Vt (8,64,S)
    __syncthreads();            // all As/Bs reads done
    u16* T = (u16*)As;          // 64 x 136 (d-major, +8 pad)
    const int h = (n0 - 2560) >> 6;
#pragma unroll
    for (int i = 0; i < 2; i++)
#pragma unroll
      for (int j = 0; j < 4; j++)
#pragma unroll
        for (int r = 0; r < 4; r++){
          int s = w*32 + i*16 + g*4 + r;      // 0..127 block-local
          int d = j*16 + mm;
          T[d*136 + s] = f2b(acc[i][j][r]);
        }
    __syncthreads();
#pragma unroll
    for (int it = 0; it < 4; it++){
      int u  = t + it*256;
      int d  = u >> 4, ch = (u & 15) * 8;
      *(uint4*)&Vtp[((size_t)h*HD + d)*S_LEN + m0 + ch] = *(const uint4*)&T[d*136 + ch];
    }
  } else {
    float* C = (float*)Cv;
#pragma unroll
    for (int i = 0; i < 2; i++)
#pragma unroll
      for (int j = 0; j < 4; j++)
#pragma unroll
        for (int r = 0; r < 4; r++)
          C[(size_t)(m0 + w*32 + i*16 + g*4 + r) * N + n0 + j*16 + mm] = acc[i][j][r];
  }
}

// Fused differential flash attention, 8 waves/block — R11 structure
// (4-deep K/V LDS buffers, prefetch distance 2, counted vmcnt waits,
// no mid-iteration barrier, setprio around MFMA clusters, seg loop
// 31-p then p). R13: truncating bf16 P-store. R14: exp2f with folded
// scale (one v_mul instead of two per exp).
__global__ __launch_bounds__(512) void attn_fused(
    const u16* __restrict__ Qbf, const u16* __restrict__ Kbf, const u16* __restrict__ Vt,
    const float* __restrict__ lq1, const float* __restrict__ lk1,
    const float* __restrict__ lq2, const float* __restrict__ lk2,
    u16* __restrict__ Ctx)
{
  __shared__ __attribute__((aligned(16))) u16 SM[74752];   // 149504 B
  u16* QPa = SM;                  // 64 x 72 (Q then P, head a)
  u16* QPb = SM + 4608;           // 64 x 72 (head b)
  u16* Ksf = SM + 9216;           // [head:2][buf:4][64][64] u16 (64 KiB)
  u16* Vs  = SM + 41984;          // [buf:4][128][64] u16 (64 KiB)
  float* OLDS = (float*)(SM + 9216);  // 64 x 128 fp32 (32 KiB), overlays Ksf

  const int p   = blockIdx.x;                 // 0..15
  const int hp  = blockIdx.y;                 // 0..15
  const int kva = hp >> 2, kvb = kva + 4;
  const int t   = threadIdx.x, w = t >> 6, lane = t & 63;
  const int hb  = w >> 2;                     // 0 = head a, 1 = head b
  const int wq  = w & 3;                      // q-row group
  const int mm  = lane & 15, g = lane >> 4, g8 = g * 8;
  const int sr  = t >> 3;                     // staging row 0..63
  const int sc  = t & 7;
  const int so  = sc * 8;
  const int x0  = ((g ^ (mm & 7)) * 8);
  const int x1  = (((g + 4) ^ (mm & 7)) * 8);
  const int ce  = ((sc ^ (sr & 7)) * 8);      // XOR chunk swizzle for staging

  u16* QP = hb ? QPb : QPa;

  float lp1 = lq1[lane] * lk1[lane];
  float lp2 = lq2[lane] * lk2[lane];
#pragma unroll
  for (int off = 1; off < 64; off <<= 1){
    lp1 += __shfl_xor(lp1, off);
    lp2 += __shfl_xor(lp2, off);
  }
  const float lam = __expf(lp1) - __expf(lp2) + LAMBDA_INIT;

// stage K/V tile kk into LDS buffer (kk/64)&3 (4 gld16 per thread)
#define TILE_ISSUE(kk) do { \
    const int tb_ = ((kk) >> 6) & 3; \
    gld16(Kbf + ((size_t)kva * S_LEN + (kk) + sr) * HD + ce, Ksf + tb_*4096 + (w*8)*64); \
    gld16(Kbf + ((size_t)kvb * S_LEN + (kk) + sr) * HD + ce, Ksf + 16384 + tb_*4096 + (w*8)*64); \
    gld16(Vt  + ((size_t)kva * HD + sr) * S_LEN + (kk) + ce, Vs + tb_*8192 + (w*8)*64); \
    gld16(Vt  + ((size_t)kvb * HD + sr) * S_LEN + (kk) + ce, Vs + tb_*8192 + (w*8 + 64)*64); \
  } while(0)

  for (int seg = 0; seg < 2; seg++){
    const int qt = seg ? p : (31 - p);
    const int q0 = qt * 64;

    __syncthreads();   // prior segment fully done (incl. OLDS reads) before restage
    // issue tiles 0 and 1; stage Q with plain stores
    TILE_ISSUE(0);
    if (64 <= q0) TILE_ISSUE(64);
    *(uint4*)&QPa[sr*72 + so] = *(const uint4*)&Qbf[((size_t)hp        * S_LEN + q0 + sr) * HD + so];
    *(uint4*)&QPb[sr*72 + so] = *(const uint4*)&Qbf[((size_t)(hp + 16) * S_LEN + q0 + sr) * HD + so];
    __syncthreads();   // Q visible, tiles 0,1 drained (full barrier drains vmcnt)
    v8s qa0 = *(const v8s*)&QP[(wq*16 + mm)*72 + g8];
    v8s qa1 = *(const v8s*)&QP[(wq*16 + mm)*72 + 32 + g8];

    v4f O[8];
#pragma unroll
    for (int n = 0; n < 8; n++) O[n] = (v4f){0.f,0.f,0.f,0.f};
    float l[4] = {0.f,0.f,0.f,0.f};

    for (int k0 = 0; k0 <= q0; k0 += 64){
      const int cur = (k0 >> 6) & 3;
      if (k0){
        // tile k0 was issued 2 iterations ago. Wait ONLY its 4 loads:
        // outstanding = tile k0 (4) + tile k0+64 (4, if issued) -> vmcnt(4)
        // keeps the newer tile in flight. Final iter: nothing newer, drain 0.
        if (k0 + 64 <= q0) asm volatile("s_waitcnt vmcnt(4)" ::: "memory");
        else               asm volatile("s_waitcnt vmcnt(0)" ::: "memory");
        __builtin_amdgcn_s_barrier();
        __builtin_amdgcn_sched_barrier(0);
      }
      // issue tile k0+128 (prefetch distance 2); buffer (k0/64+2)&3 was last
      // read in iter k0-128, two barriers ago -> WAR safe.
      if (k0 + 128 <= q0) TILE_ISSUE(k0 + 128);

      const u16* Kh = Ksf + hb*16384 + cur*4096;
      const bool dg = (k0 == q0);
      v4f S[4];
      __builtin_amdgcn_s_setprio(1);
#pragma unroll
      for (int n = 0; n < 4; n++){
        int row = n*16 + mm;
        v8s kb0 = *(const v8s*)&Kh[row*64 + x0];
        v8s kb1 = *(const v8s*)&Kh[row*64 + x1];
        v4f z = (v4f){0.f,0.f,0.f,0.f};
        z = __builtin_amdgcn_mfma_f32_16x16x32_bf16(qa0, kb0, z, 0, 0, 0);
        z = __builtin_amdgcn_mfma_f32_16x16x32_bf16(qa1, kb1, z, 0, 0, 0);
        S[n] = z;
      }
      __builtin_amdgcn_s_setprio(0);
      // P is wave-private (rows wq*16..wq*16+15): no barrier around store/reload
#pragma unroll
      for (int n = 0; n < 4; n++)
#pragma unroll
        for (int r = 0; r < 4; r++){
          float pe = exp2f(S[n][r] * EXP2_SCALE);
          if (dg && (n*16 + mm > wq*16 + g*4 + r)) pe = 0.f;
          l[r] += pe;
          QP[(wq*16 + g*4 + r)*72 + n*16 + mm] = f2b_t(pe);
        }
      v8s pa0 = *(const v8s*)&QP[(wq*16 + mm)*72 + g8];
      v8s pa1 = *(const v8s*)&QP[(wq*16 + mm)*72 + 32 + g8];
      const u16* Vh = Vs + cur*8192;
      __builtin_amdgcn_s_setprio(1);
#pragma unroll
      for (int n = 0; n < 8; n++){
        int row = n*16 + mm;
        v8s vb0 = *(const v8s*)&Vh[row*64 + x0];
        v8s vb1 = *(const v8s*)&Vh[row*64 + x1];
        O[n] = __builtin_amdgcn_mfma_f32_16x16x32_bf16(pa0, vb0, O[n], 0, 0, 0);
        O[n] = __builtin_amdgcn_mfma_f32_16x16x32_bf16(pa1, vb1, O[n], 0, 0, 0);
      }
      __builtin_amdgcn_s_setprio(0);
    }
#undef TILE_ISSUE

    // ---- epilogue for this segment ----
#pragma unroll
    for (int off = 1; off < 16; off <<= 1)
#pragma unroll
      for (int r = 0; r < 4; r++)
        l[r] += __shfl_xor(l[r], off);
    float il[4];
#pragma unroll
    for (int r = 0; r < 4; r++) il[r] = hb ? (lam / l[r]) : (1.0f / l[r]);

    __syncthreads();   // all QK reads of Ks done; OLDS may overwrite K bufs
    if (hb){
#pragma unroll
      for (int n = 0; n < 8; n++)
#pragma unroll
        for (int r = 0; r < 4; r++)
          OLDS[(wq*16 + g*4 + r)*128 + n*16 + mm] = O[n][r] * il[r];
    }
    __syncthreads();
    if (!hb){
      float av[8][4];
      float ss[4] = {0.f,0.f,0.f,0.f};
#pragma unroll
      for (int n = 0; n < 8; n++)
#pragma unroll
        for (int r = 0; r < 4; r++){
          float a = O[n][r] * il[r] - OLDS[(wq*16 + g*4 + r)*128 + n*16 + mm];
          av[n][r] = a;
          ss[r] += a * a;
        }
#pragma unroll
      for (int off = 1; off < 16; off <<= 1)
#pragma unroll
        for (int r = 0; r < 4; r++)
          ss[r] += __shfl_xor(ss[r], off);
      float rv[4];
#pragma unroll
      for (int r = 0; r < 4; r++)
        rv[r] = rsqrtf(ss[r] * (1.0f/128.0f) + 1e-6f) * ONE_MINUS_LI;
#pragma unroll
      for (int n = 0; n < 8; n++)
#pragma unroll
        for (int r = 0; r < 4; r++){
          int srow = q0 + wq*16 + g*4 + r;
          Ctx[(size_t)srow * HID + hp * DVV + n*16 + mm] = f2b(av[n][r] * rv[r]);
        }
    }
  }
}

extern "C" void kernel_launch(void* const* d_in, const int* in_sizes, int n_in,
                              void* d_out, int out_size, void* d_ws, size_t ws_size,
                              hipStream_t stream)
{
  (void)in_sizes; (void)n_in; (void)out_size; (void)ws_size;
  const float* hs   = (const float*)d_in[0];
  const float* cosb = (const float*)d_in[1];
  const float* sinb = (const float*)d_in[2];
  const float* Wq   = (const float*)d_in[3];
  const float* Wk   = (const float*)d_in[4];
  const float* Wv   = (const float*)d_in[5];
  const float* Wo   = (const float*)d_in[6];
  const float* lq1  = (const float*)d_in[7];
  const float* lk1  = (const float*)d_in[8];
  const float* lq2  = (const float*)d_in[9];
  const float* lk2  = (const float*)d_in[10];

  char* ws = (char*)d_ws;
  u16* hsb   = (u16*)(ws);                   // [0,8) MB bf16 hs
  u16* Wqkvb = (u16*)(ws + (8u  << 20));     // [8,20) bf16 [Wq;Wk;Wv] 3072x2048
  u16* Ctx   = (u16*)(ws + (20u << 20));     // [20,28) bf16 Ctx (S,2048)
  u16* Wob   = (u16*)(ws + (32u << 20));     // [32,40) bf16 Wo
  u16* Kbf   = (u16*)(ws + (44u << 20));     // [44,46) bf16 (8,S,64)
  u16* Vt    = (u16*)(ws + (46u << 20));     // [46,48) bf16 (8,64,S)
  u16* Qbf   = (u16*)(ws + (48u << 20));     // [48,56) bf16 (32,S,64)

  cast5<<<7168, 256, 0, stream>>>(hs, Wq, Wk, Wv, Wo, hsb, Wqkvb, Wob);
  gemm_bf16<2, 2><<<dim3(48, 16), 256, 0, stream>>>(hsb, Wqkvb, nullptr, S_LEN, 3072, HID,
                                                    cosb, sinb, Qbf, Kbf, Vt);
  attn_fused<<<dim3(16, 16), 512, 0, stream>>>(Qbf, Kbf, Vt, lq1, lk1, lq2, lk2, Ctx);
  gemm_bf16<0, 3><<<dim3(32, 16), 256, 0, stream>>>(Ctx, Wob, (float*)d_out, S_LEN, 2048, HID,
                                                    nullptr, nullptr, nullptr, nullptr, nullptr);
}

// Round 16
// 220.644 us; speedup vs baseline: 1.0184x; 1.0184x over previous
//
#include <hip/hip_runtime.h>

typedef unsigned short u16;
typedef __attribute__((ext_vector_type(8))) short v8s;
typedef __attribute__((ext_vector_type(4))) float v4f;

#define S_LEN 2048
#define HID   2048
#define NH    32
#define NKV   8
#define HD    64
#define DVV   128
#define LAMBDA_INIT  0.7455692280263525f
#define ONE_MINUS_LI 0.2544307719736475f

__device__ __forceinline__ u16 f2b(float f){
  union { float f; unsigned int i; } v; v.f = f;
  unsigned int x = v.i;
  unsigned int r = (x + 0x7fffu + ((x >> 16) & 1u)) >> 16;
  return (u16)r;
}
// truncating bf16 (P-store only: P>=0, feeds PV matmul; saves 3 VALU/value)
__device__ __forceinline__ u16 f2b_t(float f){
  union { float f; unsigned int i; } v; v.f = f;
  return (u16)(v.i >> 16);
}
__device__ __forceinline__ float b2f(u16 u){
  union { unsigned int i; float f; } v; v.i = ((unsigned int)u) << 16; return v.f;
}

__device__ __forceinline__ void gld16(const u16* g, u16* l){
  __builtin_amdgcn_global_load_lds(
      (const __attribute__((address_space(1))) unsigned int*)g,
      (__attribute__((address_space(3))) unsigned int*)l, 16, 0, 0);
}

// one launch casting hs, Wq, Wk, Wv, Wo to bf16 (regions by blockIdx)
__global__ __launch_bounds__(256) void cast5(
    const float* __restrict__ hs, const float* __restrict__ Wq,
    const float* __restrict__ Wk, const float* __restrict__ Wv,
    const float* __restrict__ Wo,
    u16* __restrict__ hsb, u16* __restrict__ Wqkvb, u16* __restrict__ Wob)
{
  int b = blockIdx.x;
  const float* S; u16* D; int rb;
  if (b < 2048)      { S = hs; D = hsb;             rb = b; }
  else if (b < 4096) { S = Wq; D = Wqkvb;           rb = b - 2048; }
  else if (b < 4608) { S = Wk; D = Wqkvb + 4194304; rb = b - 4096; }
  else if (b < 5120) { S = Wv; D = Wqkvb + 5242880; rb = b - 4608; }
  else               { S = Wo; D = Wob;             rb = b - 5120; }
  size_t i = ((size_t)rb * 256 + threadIdx.x) * 8;
  float4 a = *(const float4*)(S + i);
  float4 c = *(const float4*)(S + i + 4);
  u16 o[8] = {f2b(a.x), f2b(a.y), f2b(a.z), f2b(a.w), f2b(c.x), f2b(c.y), f2b(c.z), f2b(c.w)};
  *(uint4*)(D + i) = *(const uint4*)o;
}

// C[m][n] = sum_k A[m*K+k]*B[n*K+k]; A,B bf16.
// 128x64 tile, BK=64, DEPTH-buffered LDS (DEPTH=2: 48 KB -> 3 blocks/CU;
// DEPTH=3: 72 KB -> 2 blocks/CU with counted vmcnt(6) waits = 2 iters of
// load slack). gemm<2> uses DEPTH=2 (occupancy 3 wins, R12 lesson);
// gemm<0> uses DEPTH=3 (occupancy already 2 -> pipeline depth is free;
// R14 measured ~3 us gain).
// MODE 0: C fp32 to Cv.
// MODE 2: fused QKV epilogue — Q cols (n0<2048) / K cols (2048..2559) get
// RoPE in registers -> Qbf/Kbf (h,s,d); V cols (n0>=2560) transposed through
// LDS (reusing As) -> Vt (8,64,S).
template<int MODE, int DEPTH>
__global__ __launch_bounds__(256) void gemm_bf16(const u16* __restrict__ A, const u16* __restrict__ B,
                                                 void* __restrict__ Cv, int M, int N, int K,
                                                 const float* __restrict__ cosb, const float* __restrict__ sinb,
                                                 u16* __restrict__ Qbf, u16* __restrict__ Kbf,
                                                 u16* __restrict__ Vtp)
{
  __shared__ __attribute__((aligned(16))) u16 As[DEPTH][128*64];
  __shared__ __attribute__((aligned(16))) u16 Bs[DEPTH][64*64];
  const int t    = threadIdx.x;
  const int w    = t >> 6, lane = t & 63;
  const int mm   = lane & 15, g = lane >> 4;
  const int m0   = blockIdx.y * 128, n0 = blockIdx.x * 64;
  const int lr   = lane >> 3;      // 0..7
  const int sch  = lane & 7;

  v4f acc[2][4];
#pragma unroll
  for (int i = 0; i < 2; i++)
#pragma unroll
    for (int j = 0; j < 4; j++) acc[i][j] = (v4f){0.f,0.f,0.f,0.f};

// 6 gld16 per thread per stage (4 A + 2 B) — vmcnt counting relies on this
#define G_STAGE(kk, buf) do { \
    _Pragma("unroll") \
    for (int i = 0; i < 4; i++){ \
      int r  = w*32 + lr + i*8; \
      int ce = ((sch ^ (r & 7)) * 8); \
      gld16(A + (size_t)(m0 + r) * K + (kk) + ce, &As[buf][w*2048 + i*512]); \
    } \
    _Pragma("unroll") \
    for (int i = 0; i < 2; i++){ \
      int r  = w*16 + lr + i*8; \
      int ce = ((sch ^ (r & 7)) * 8); \
      gld16(B + (size_t)(n0 + r) * K + (kk) + ce, &Bs[buf][w*1024 + i*512]); \
    } \
  } while(0)

  // prologue: stage tile 0 (and tile 1 for DEPTH=3), full drain
  G_STAGE(0, 0);
  if (DEPTH >= 3 && 64 < K) G_STAGE(64, 1);
  __syncthreads();

  for (int k0 = 0; k0 < K; k0 += 64){
    const int cur = (k0 >> 6) % DEPTH;
    if (k0){
      if (DEPTH >= 3 && k0 + 64 < K){
        // tile k0 + tile k0+64 outstanding (6 each): wait only tile k0's
        asm volatile("s_waitcnt vmcnt(6)" ::: "memory");
      } else {
        asm volatile("s_waitcnt vmcnt(0)" ::: "memory");
      }
      __builtin_amdgcn_s_barrier();
      __builtin_amdgcn_sched_barrier(0);
    }
    if (DEPTH == 2){
      if (k0 + 64 < K) G_STAGE(k0 + 64, cur ^ 1);
    } else {
      if (k0 + 128 < K) G_STAGE(k0 + 128, ((k0 >> 6) + 2) % DEPTH);
    }

#pragma unroll
    for (int kc = 0; kc < 2; kc++){
      v8s af[2], bf[4];
#pragma unroll
      for (int i = 0; i < 2; i++){
        int r = w*32 + i*16 + mm;
        af[i] = *(const v8s*)&As[cur][r*64 + (((kc*4 + g) ^ (r & 7)) * 8)];
      }
#pragma unroll
      for (int j = 0; j < 4; j++){
        int r = j*16 + mm;
        bf[j] = *(const v8s*)&Bs[cur][r*64 + (((kc*4 + g) ^ (r & 7)) * 8)];
      }
#pragma unroll
      for (int i = 0; i < 2; i++)
#pragma unroll
        for (int j = 0; j < 4; j++)
          acc[i][j] = __builtin_amdgcn_mfma_f32_16x16x32_bf16(af[i], bf[j], acc[i][j], 0, 0, 0);
    }
  }
#undef G_STAGE

  if (MODE == 2 && n0 < 2560){
    // Q or K columns: RoPE in registers, write (h,s,d) layout
    u16* base = (n0 < 2048) ? (Qbf + (size_t)(n0 >> 6) * S_LEN * HD)
                            : (Kbf + (size_t)((n0 - 2048) >> 6) * S_LEN * HD);
#pragma unroll
    for (int i = 0; i < 2; i++)
#pragma unroll
      for (int j = 0; j < 2; j++)
#pragma unroll
        for (int r = 0; r < 4; r++){
          int s = m0 + w*32 + i*16 + g*4 + r;
          int d = j*16 + mm;
          float x1 = acc[i][j][r], x2 = acc[i][j+2][r];
          float c1 = cosb[s*HD + d],      s1 = sinb[s*HD + d];
          float c2 = cosb[s*HD + d + 32], s2 = sinb[s*HD + d + 32];
          base[(size_t)s*HD + d]      = f2b(x1*c1 - x2*s1);
          base[(size_t)s*HD + d + 32] = f2b(x2*c2 + x1*s2);
        }
  } else if (MODE == 2){
    // V columns: transpose through LDS (As is dead) -> Vt (8,64,S)
    __syncthreads();            // all As/Bs reads done
    u16* T = (u16*)As;          // 64 x 136 (d-major, +8 pad)
    const int h = (n0 - 2560) >> 6;
#pragma unroll
    for (int i = 0; i < 2; i++)
#pragma unroll
      for (int j = 0; j < 4; j++)
#pragma unroll
        for (int r = 0; r < 4; r++){
          int s = w*32 + i*16 + g*4 + r;      // 0..127 block-local
          int d = j*16 + mm;
          T[d*136 + s] = f2b(acc[i][j][r]);
        }
    __syncthreads();
#pragma unroll
    for (int it = 0; it < 4; it++){
      int u  = t + it*256;
      int d  = u >> 4, ch = (u & 15) * 8;
      *(uint4*)&Vtp[((size_t)h*HD + d)*S_LEN + m0 + ch] = *(const uint4*)&T[d*136 + ch];
    }
  } else {
    float* C = (float*)Cv;
#pragma unroll
    for (int i = 0; i < 2; i++)
#pragma unroll
      for (int j = 0; j < 4; j++)
#pragma unroll
        for (int r = 0; r < 4; r++)
          C[(size_t)(m0 + w*32 + i*16 + g*4 + r) * N + n0 + j*16 + mm] = acc[i][j][r];
  }
}

// Fused differential flash attention, 8 waves/block — R11 structure
// (4-deep K/V LDS buffers, prefetch distance 2, counted vmcnt waits,
// no mid-iteration barrier, setprio around MFMA clusters, seg loop
// 31-p then p). R13: truncating bf16 P-store. R15: __expf restored
// (R14's exp2f regressed — precise-OCML path, not v_exp_f32).
__global__ __launch_bounds__(512) void attn_fused(
    const u16* __restrict__ Qbf, const u16* __restrict__ Kbf, const u16* __restrict__ Vt,
    const float* __restrict__ lq1, const float* __restrict__ lk1,
    const float* __restrict__ lq2, const float* __restrict__ lk2,
    u16* __restrict__ Ctx)
{
  __shared__ __attribute__((aligned(16))) u16 SM[74752];   // 149504 B
  u16* QPa = SM;                  // 64 x 72 (Q then P, head a)
  u16* QPb = SM + 4608;           // 64 x 72 (head b)
  u16* Ksf = SM + 9216;           // [head:2][buf:4][64][64] u16 (64 KiB)
  u16* Vs  = SM + 41984;          // [buf:4][128][64] u16 (64 KiB)
  float* OLDS = (float*)(SM + 9216);  // 64 x 128 fp32 (32 KiB), overlays Ksf

  const int p   = blockIdx.x;                 // 0..15
  const int hp  = blockIdx.y;                 // 0..15
  const int kva = hp >> 2, kvb = kva + 4;
  const int t   = threadIdx.x, w = t >> 6, lane = t & 63;
  const int hb  = w >> 2;                     // 0 = head a, 1 = head b
  const int wq  = w & 3;                      // q-row group
  const int mm  = lane & 15, g = lane >> 4, g8 = g * 8;
  const int sr  = t >> 3;                     // staging row 0..63
  const int sc  = t & 7;
  const int so  = sc * 8;
  const int x0  = ((g ^ (mm & 7)) * 8);
  const int x1  = (((g + 4) ^ (mm & 7)) * 8);
  const int ce  = ((sc ^ (sr & 7)) * 8);      // XOR chunk swizzle for staging

  u16* QP = hb ? QPb : QPa;

  float lp1 = lq1[lane] * lk1[lane];
  float lp2 = lq2[lane] * lk2[lane];
#pragma unroll
  for (int off = 1; off < 64; off <<= 1){
    lp1 += __shfl_xor(lp1, off);
    lp2 += __shfl_xor(lp2, off);
  }
  const float lam = __expf(lp1) - __expf(lp2) + LAMBDA_INIT;

// stage K/V tile kk into LDS buffer (kk/64)&3 (4 gld16 per thread)
#define TILE_ISSUE(kk) do { \
    const int tb_ = ((kk) >> 6) & 3; \
    gld16(Kbf + ((size_t)kva * S_LEN + (kk) + sr) * HD + ce, Ksf + tb_*4096 + (w*8)*64); \
    gld16(Kbf + ((size_t)kvb * S_LEN + (kk) + sr) * HD + ce, Ksf + 16384 + tb_*4096 + (w*8)*64); \
    gld16(Vt  + ((size_t)kva * HD + sr) * S_LEN + (kk) + ce, Vs + tb_*8192 + (w*8)*64); \
    gld16(Vt  + ((size_t)kvb * HD + sr) * S_LEN + (kk) + ce, Vs + tb_*8192 + (w*8 + 64)*64); \
  } while(0)

  for (int seg = 0; seg < 2; seg++){
    const int qt = seg ? p : (31 - p);
    const int q0 = qt * 64;

    __syncthreads();   // prior segment fully done (incl. OLDS reads) before restage
    // issue tiles 0 and 1; stage Q with plain stores
    TILE_ISSUE(0);
    if (64 <= q0) TILE_ISSUE(64);
    *(uint4*)&QPa[sr*72 + so] = *(const uint4*)&Qbf[((size_t)hp        * S_LEN + q0 + sr) * HD + so];
    *(uint4*)&QPb[sr*72 + so] = *(const uint4*)&Qbf[((size_t)(hp + 16) * S_LEN + q0 + sr) * HD + so];
    __syncthreads();   // Q visible, tiles 0,1 drained (full barrier drains vmcnt)
    v8s qa0 = *(const v8s*)&QP[(wq*16 + mm)*72 + g8];
    v8s qa1 = *(const v8s*)&QP[(wq*16 + mm)*72 + 32 + g8];

    v4f O[8];
#pragma unroll
    for (int n = 0; n < 8; n++) O[n] = (v4f){0.f,0.f,0.f,0.f};
    float l[4] = {0.f,0.f,0.f,0.f};

    for (int k0 = 0; k0 <= q0; k0 += 64){
      const int cur = (k0 >> 6) & 3;
      if (k0){
        // tile k0 was issued 2 iterations ago. Wait ONLY its 4 loads:
        // outstanding = tile k0 (4) + tile k0+64 (4, if issued) -> vmcnt(4)
        // keeps the newer tile in flight. Final iter: nothing newer, drain 0.
        if (k0 + 64 <= q0) asm volatile("s_waitcnt vmcnt(4)" ::: "memory");
        else               asm volatile("s_waitcnt vmcnt(0)" ::: "memory");
        __builtin_amdgcn_s_barrier();
        __builtin_amdgcn_sched_barrier(0);
      }
      // issue tile k0+128 (prefetch distance 2); buffer (k0/64+2)&3 was last
      // read in iter k0-128, two barriers ago -> WAR safe.
      if (k0 + 128 <= q0) TILE_ISSUE(k0 + 128);

      const u16* Kh = Ksf + hb*16384 + cur*4096;
      const bool dg = (k0 == q0);
      v4f S[4];
      __builtin_amdgcn_s_setprio(1);
#pragma unroll
      for (int n = 0; n < 4; n++){
        int row = n*16 + mm;
        v8s kb0 = *(const v8s*)&Kh[row*64 + x0];
        v8s kb1 = *(const v8s*)&Kh[row*64 + x1];
        v4f z = (v4f){0.f,0.f,0.f,0.f};
        z = __builtin_amdgcn_mfma_f32_16x16x32_bf16(qa0, kb0, z, 0, 0, 0);
        z = __builtin_amdgcn_mfma_f32_16x16x32_bf16(qa1, kb1, z, 0, 0, 0);
        S[n] = z;
      }
      __builtin_amdgcn_s_setprio(0);
      // P is wave-private (rows wq*16..wq*16+15): no barrier around store/reload
#pragma unroll
      for (int n = 0; n < 4; n++)
#pragma unroll
        for (int r = 0; r < 4; r++){
          float pe = __expf(S[n][r] * 0.125f);
          if (dg && (n*16 + mm > wq*16 + g*4 + r)) pe = 0.f;
          l[r] += pe;
          QP[(wq*16 + g*4 + r)*72 + n*16 + mm] = f2b_t(pe);
        }
      v8s pa0 = *(const v8s*)&QP[(wq*16 + mm)*72 + g8];
      v8s pa1 = *(const v8s*)&QP[(wq*16 + mm)*72 + 32 + g8];
      const u16* Vh = Vs + cur*8192;
      __builtin_amdgcn_s_setprio(1);
#pragma unroll
      for (int n = 0; n < 8; n++){
        int row = n*16 + mm;
        v8s vb0 = *(const v8s*)&Vh[row*64 + x0];
        v8s vb1 = *(const v8s*)&Vh[row*64 + x1];
        O[n] = __builtin_amdgcn_mfma_f32_16x16x32_bf16(pa0, vb0, O[n], 0, 0, 0);
        O[n] = __builtin_amdgcn_mfma_f32_16x16x32_bf16(pa1, vb1, O[n], 0, 0, 0);
      }
      __builtin_amdgcn_s_setprio(0);
    }
#undef TILE_ISSUE

    // ---- epilogue for this segment ----
#pragma unroll
    for (int off = 1; off < 16; off <<= 1)
#pragma unroll
      for (int r = 0; r < 4; r++)
        l[r] += __shfl_xor(l[r], off);
    float il[4];
#pragma unroll
    for (int r = 0; r < 4; r++) il[r] = hb ? (lam / l[r]) : (1.0f / l[r]);

    __syncthreads();   // all QK reads of Ks done; OLDS may overwrite K bufs
    if (hb){
#pragma unroll
      for (int n = 0; n < 8; n++)
#pragma unroll
        for (int r = 0; r < 4; r++)
          OLDS[(wq*16 + g*4 + r)*128 + n*16 + mm] = O[n][r] * il[r];
    }
    __syncthreads();
    if (!hb){
      float av[8][4];
      float ss[4] = {0.f,0.f,0.f,0.f};
#pragma unroll
      for (int n = 0; n < 8; n++)
#pragma unroll
        for (int r = 0; r < 4; r++){
          float a = O[n][r] * il[r] - OLDS[(wq*16 + g*4 + r)*128 + n*16 + mm];
          av[n][r] = a;
          ss[r] += a * a;
        }
#pragma unroll
      for (int off = 1; off < 16; off <<= 1)
#pragma unroll
        for (int r = 0; r < 4; r++)
          ss[r] += __shfl_xor(ss[r], off);
      float rv[4];
#pragma unroll
      for (int r = 0; r < 4; r++)
        rv[r] = rsqrtf(ss[r] * (1.0f/128.0f) + 1e-6f) * ONE_MINUS_LI;
#pragma unroll
      for (int n = 0; n < 8; n++)
#pragma unroll
        for (int r = 0; r < 4; r++){
          int srow = q0 + wq*16 + g*4 + r;
          Ctx[(size_t)srow * HID + hp * DVV + n*16 + mm] = f2b(av[n][r] * rv[r]);
        }
    }
  }
}

extern "C" void kernel_launch(void* const* d_in, const int* in_sizes, int n_in,
                              void* d_out, int out_size, void* d_ws, size_t ws_size,
                              hipStream_t stream)
{
  (void)in_sizes; (void)n_in; (void)out_size; (void)ws_size;
  const float* hs   = (const float*)d_in[0];
  const float* cosb = (const float*)d_in[1];
  const float* sinb = (const float*)d_in[2];
  const float* Wq   = (const float*)d_in[3];
  const float* Wk   = (const float*)d_in[4];
  const float* Wv   = (const float*)d_in[5];
  const float* Wo   = (const float*)d_in[6];
  const float* lq1  = (const float*)d_in[7];
  const float* lk1  = (const float*)d_in[8];
  const float* lq2  = (const float*)d_in[9];
  const float* lk2  = (const float*)d_in[10];

  char* ws = (char*)d_ws;
  u16* hsb   = (u16*)(ws);                   // [0,8) MB bf16 hs
  u16* Wqkvb = (u16*)(ws + (8u  << 20));     // [8,20) bf16 [Wq;Wk;Wv] 3072x2048
  u16* Ctx   = (u16*)(ws + (20u << 20));     // [20,28) bf16 Ctx (S,2048)
  u16* Wob   = (u16*)(ws + (32u << 20));     // [32,40) bf16 Wo
  u16* Kbf   = (u16*)(ws + (44u << 20));     // [44,46) bf16 (8,S,64)
  u16* Vt    = (u16*)(ws + (46u << 20));     // [46,48) bf16 (8,64,S)
  u16* Qbf   = (u16*)(ws + (48u << 20));     // [48,56) bf16 (32,S,64)

  cast5<<<7168, 256, 0, stream>>>(hs, Wq, Wk, Wv, Wo, hsb, Wqkvb, Wob);
  gemm_bf16<2, 2><<<dim3(48, 16), 256, 0, stream>>>(hsb, Wqkvb, nullptr, S_LEN, 3072, HID,
                                                    cosb, sinb, Qbf, Kbf, Vt);
  attn_fused<<<dim3(16, 16), 512, 0, stream>>>(Qbf, Kbf, Vt, lq1, lk1, lq2, lk2, Ctx);
  gemm_bf16<0, 3><<<dim3(32, 16), 256, 0, stream>>>(Ctx, Wob, (float*)d_out, S_LEN, 2048, HID,
                                                    nullptr, nullptr, nullptr, nullptr, nullptr);
}